// Round 10
// baseline (437.151 us; speedup 1.0000x reference)
//
#include <hip/hip_runtime.h>

// ---------------------------------------------------------------------------
// GCNnet: 3x GCNConv (40->40->80->128) + global max pool + MLP(128->512->2) + softmax
// N=100000 nodes, E=1600000 edges, G=512 graphs.
// Round 9:
//  - f2bf folded into deg_count (atomic-bound kernel, 99% idle -> free work).
//  - gather: thread = (node, 8 feats) (TPN=F/8, was F/4): halves redundant
//    perm/offs reads per edge; H row read = one 16B uint4 (rows 16B-aligned),
//    bf16 unpack via shift/mask (1 op/elem).
//  - g-zeroing folded into scanB.
//  - deg_count atomic is at the device-atomic op-throughput ceiling
//    (R3: 2 ops/edge=141us, R4: 1 op/edge=74.6us -> op-count scaling).
// ---------------------------------------------------------------------------

static inline int cdiv(long a, int b) { return (int)((a + b - 1) / b); }
static inline size_t align256(size_t x) { return (x + 255) & ~(size_t)255; }

#define FXSCALE 16777216.0f           // 2^24
#define FXMASK  ((1ULL << 40) - 1)
#define SCHUNK  1024                  // elements per scan block

__device__ __forceinline__ unsigned short f2bf(float f) {   // round-nearest-even
    unsigned int u = __float_as_uint(f);
    return (unsigned short)((u + 0x7FFFu + ((u >> 16) & 1u)) >> 16);
}

// one u64 atomic per edge: high 24 bits count, low 40 bits fixed-point weight sum.
// old >> 40 = this edge's rank within its destination segment.
// Threads e < nx4 also convert one float4 of x -> bf16 (free under atomic latency).
__global__ void deg_count_kernel(const int* __restrict__ col, const float* __restrict__ w,
                                 unsigned long long* __restrict__ packed,
                                 int* __restrict__ rank, int E,
                                 const float* __restrict__ x, ushort* __restrict__ xbf,
                                 int nx4) {
    int e = blockIdx.x * blockDim.x + threadIdx.x;
    if (e < nx4) {
        float4 v = ((const float4*)x)[e];
        ((ushort4*)xbf)[e] = make_ushort4(f2bf(v.x), f2bf(v.y), f2bf(v.z), f2bf(v.w));
    }
    if (e >= E) return;
    int c = col[e];
    unsigned long long fx = (unsigned long long)llrintf(w[e] * FXSCALE);
    unsigned long long old = atomicAdd(&packed[c], (1ULL << 40) | fx);
    rank[e] = (int)(old >> 40);
}

// scan phase A: per-block count sums + dinv (256 thr x 4 elems = 1024/block)
__global__ void scanA_kernel(const unsigned long long* __restrict__ packed,
                             float* __restrict__ dinv, int* __restrict__ blockSums, int N) {
    __shared__ int wred[4];
    int tid = threadIdx.x, lane = tid & 63, wid = tid >> 6;
    int i0 = blockIdx.x * SCHUNK + tid * 4;
    int s = 0;
#pragma unroll
    for (int k = 0; k < 4; ++k) {
        int i = i0 + k;
        if (i < N) {
            unsigned long long p = packed[i];
            s += (int)(p >> 40);
            float deg = (float)(p & FXMASK) * (1.0f / FXSCALE);
            dinv[i] = rsqrtf(deg + 1.0f);
        }
    }
#pragma unroll
    for (int off = 32; off > 0; off >>= 1) s += __shfl_down(s, off, 64);
    if (lane == 0) wred[wid] = s;
    __syncthreads();
    if (tid == 0) blockSums[blockIdx.x] = wred[0] + wred[1] + wred[2] + wred[3];
}

// scan phase B: one block, exclusive scan of blockSums[nb] (nb <= 1024);
// writes total into offs[N]. Also zeroes the pool buffer g (idle threads).
__global__ void scanB_kernel(int* __restrict__ blockSums, int* __restrict__ offs,
                             int nb, int N, float4* __restrict__ gz, int gq) {
    __shared__ int wsum[16];
    int tid = threadIdx.x, lane = tid & 63, wid = tid >> 6;
    int v = (tid < nb) ? blockSums[tid] : 0;
    int incl = v;
#pragma unroll
    for (int off = 1; off < 64; off <<= 1) {
        int t = __shfl_up(incl, off, 64);
        if (lane >= off) incl += t;
    }
    if (lane == 63) wsum[wid] = incl;
    __syncthreads();
    if (wid == 0 && lane < 16) {
        int w = wsum[lane];
        int ic = w;
#pragma unroll
        for (int off = 1; off < 16; off <<= 1) {
            int t = __shfl_up(ic, off, 64);
            if (lane >= off) ic += t;
        }
        wsum[lane] = ic - w;   // exclusive
    }
    __syncthreads();
    if (tid < nb) blockSums[tid] = wsum[wid] + incl - v;   // exclusive prefix
    if (tid == 1023) offs[N] = wsum[15] + incl;            // grand total
    float4 z = make_float4(0.f, 0.f, 0.f, 0.f);
    for (int i = tid; i < gq; i += 1024) gz[i] = z;
}

// scan phase C: local exclusive scan + block offset -> offs
__global__ void scanC_kernel(const unsigned long long* __restrict__ packed,
                             const int* __restrict__ blockSums,
                             int* __restrict__ offs, int N) {
    __shared__ int wsum[4];
    int tid = threadIdx.x, lane = tid & 63, wid = tid >> 6;
    int i0 = blockIdx.x * SCHUNK + tid * 4;
    int v0 = 0, v1 = 0, v2 = 0, v3 = 0;
    if (i0 + 0 < N) v0 = (int)(packed[i0 + 0] >> 40);
    if (i0 + 1 < N) v1 = (int)(packed[i0 + 1] >> 40);
    if (i0 + 2 < N) v2 = (int)(packed[i0 + 2] >> 40);
    if (i0 + 3 < N) v3 = (int)(packed[i0 + 3] >> 40);
    int sum = v0 + v1 + v2 + v3;
    int incl = sum;
#pragma unroll
    for (int off = 1; off < 64; off <<= 1) {
        int t = __shfl_up(incl, off, 64);
        if (lane >= off) incl += t;
    }
    if (lane == 63) wsum[wid] = incl;
    __syncthreads();
    if (tid == 0) {
        int c = 0;
#pragma unroll
        for (int k = 0; k < 4; ++k) { int t = wsum[k]; wsum[k] = c; c += t; }
    }
    __syncthreads();
    int pre = blockSums[blockIdx.x] + wsum[wid] + (incl - sum);
    if (i0 + 0 < N) offs[i0 + 0] = pre;
    if (i0 + 1 < N) offs[i0 + 1] = pre + v0;
    if (i0 + 2 < N) offs[i0 + 2] = pre + v0 + v1;
    if (i0 + 3 < N) offs[i0 + 3] = pre + v0 + v1 + v2;
}

// CSR fill, atomic-free: pos = offs[col] + rank; perm = {row, norm bits} (8B store)
__global__ void fill_kernel(const int* __restrict__ row, const int* __restrict__ col,
                            const float* __restrict__ w, const int* __restrict__ rank,
                            const float* __restrict__ dinv, const int* __restrict__ offs,
                            int2* __restrict__ perm, int E) {
    int e = blockIdx.x * blockDim.x + threadIdx.x;
    if (e >= E) return;
    int r = row[e], c = col[e];
    int pos = offs[c] + rank[e];
    float nm = dinv[r] * w[e] * dinv[c];
    perm[pos] = make_int2(r, __float_as_int(nm));
}

// unpack-accumulate 8 bf16 (one uint4) scaled by M into A[8]
#define ACC8(A, U, M) \
    A[0] += __uint_as_float(U.x << 16) * M; A[1] += __uint_as_float(U.x & 0xffff0000u) * M; \
    A[2] += __uint_as_float(U.y << 16) * M; A[3] += __uint_as_float(U.y & 0xffff0000u) * M; \
    A[4] += __uint_as_float(U.z << 16) * M; A[5] += __uint_as_float(U.z & 0xffff0000u) * M; \
    A[6] += __uint_as_float(U.w << 16) * M; A[7] += __uint_as_float(U.w & 0xffff0000u) * M;

// agg[d] = sum_{e: col=d} H[row_e]*norm_e + dinv[d]^2*H[d]   (H in bf16)
// thread = (node, 8 feats): one 16B uint4 H-read per edge; 4-edge unroll,
// 4 independent load chains; perm/offs read redundancy = F/8 (half of R8).
template<int F>
__global__ void gather_kernel(const int* __restrict__ offs, const int2* __restrict__ perm,
                              const ushort* __restrict__ H, const float* __restrict__ dinv,
                              float* __restrict__ agg, int N) {
    constexpr int TPN = F / 8;
    int idx = blockIdx.x * blockDim.x + threadIdx.x;
    int node = idx / TPN, q = idx % TPN;
    if (node >= N) return;
    int s = offs[node], e = offs[node + 1];
    float a[8] = {0.f,0.f,0.f,0.f,0.f,0.f,0.f,0.f};
    float b[8] = {0.f,0.f,0.f,0.f,0.f,0.f,0.f,0.f};
    int j = s;
    for (; j + 4 <= e; j += 4) {
        int2 p0 = perm[j + 0], p1 = perm[j + 1], p2 = perm[j + 2], p3 = perm[j + 3];
        uint4 u0 = *(const uint4*)(H + (long)p0.x * F + q * 8);
        uint4 u1 = *(const uint4*)(H + (long)p1.x * F + q * 8);
        uint4 u2 = *(const uint4*)(H + (long)p2.x * F + q * 8);
        uint4 u3 = *(const uint4*)(H + (long)p3.x * F + q * 8);
        float m0 = __int_as_float(p0.y), m1 = __int_as_float(p1.y);
        float m2 = __int_as_float(p2.y), m3 = __int_as_float(p3.y);
        ACC8(a, u0, m0) ACC8(b, u1, m1) ACC8(a, u2, m2) ACC8(b, u3, m3)
    }
    for (; j < e; ++j) {
        int2 p = perm[j];
        uint4 u = *(const uint4*)(H + (long)p.x * F + q * 8);
        float nm = __int_as_float(p.y);
        ACC8(a, u, nm)
    }
    float di = dinv[node], d2 = di * di;
    uint4 su = *(const uint4*)(H + (long)node * F + q * 8);
    ACC8(a, su, d2)
    float* dst = agg + (long)node * F + q * 8;
    *(float4*)(dst + 0) = make_float4(a[0] + b[0], a[1] + b[1], a[2] + b[2], a[3] + b[3]);
    *(float4*)(dst + 4) = make_float4(a[4] + b[4], a[5] + b[5], a[6] + b[6], a[7] + b[7]);
}

// out[N,FOUT] = relu(X[N,K] @ W[K,FOUT] + bias)
// thread = (NPT=4 consecutive nodes, 4 feats), q-minor lanes (coalesced X/W/out);
// W staged in LDS; per W ds_read_b128: 16 FMAs. Block owns NPB consecutive nodes.
// BF16OUT: store ushort4 bf16. FUSE_POOL: hierarchical max-pool (2-graph LDS
// window, zero-skipping flush; direct global atomics if rel >= 2).
template<int K, int FOUT, int BLK, bool FUSE_POOL, bool BF16OUT>
__global__ __launch_bounds__(BLK)
void gemm_kernel(const float* __restrict__ X, const float* __restrict__ W,
                 const float* __restrict__ bias, void* __restrict__ out,
                 const int* __restrict__ batch, unsigned int* __restrict__ g, int N) {
    constexpr int NPT = 4;                 // nodes per thread
    constexpr int TPQ = FOUT / 4;          // feature-group slots
    constexpr int PSLOTS = BLK / TPQ;      // node-groups per block
    constexpr int NPB = PSLOTS * NPT;      // nodes per block
    __shared__ float wsm[K * FOUT];
    __shared__ unsigned int gma[FUSE_POOL ? 2 * FOUT : 1];
    __shared__ int gfirst;
    for (int i = threadIdx.x; i < K * FOUT; i += BLK) wsm[i] = W[i];
    if (FUSE_POOL) {
        if (threadIdx.x == 0) gfirst = batch[min((int)(blockIdx.x * NPB), N - 1)];
        for (int i = threadIdx.x; i < 2 * FOUT; i += BLK) gma[i] = 0u;
    }
    __syncthreads();

    int q = threadIdx.x % TPQ, p = threadIdx.x / TPQ;
    long nbase = (long)blockIdx.x * NPB + (long)p * NPT;

    float4 acc[NPT];
#pragma unroll
    for (int t = 0; t < NPT; ++t) acc[t] = make_float4(0.f, 0.f, 0.f, 0.f);

    const float* wq = wsm + q * 4;
#pragma unroll 4
    for (int i = 0; i < K / 4; ++i) {
        float4 xv[NPT];
#pragma unroll
        for (int t = 0; t < NPT; ++t) {
            long n = nbase + t; if (n >= N) n = N - 1;    // clamp (masked at store)
            xv[t] = *(const float4*)(X + n * K + i * 4);
        }
#pragma unroll
        for (int j = 0; j < 4; ++j) {
            float4 wv = *(const float4*)(wq + (i * 4 + j) * FOUT);
#pragma unroll
            for (int t = 0; t < NPT; ++t) {
                float v = ((const float*)&xv[t])[j];
                acc[t].x += v * wv.x; acc[t].y += v * wv.y;
                acc[t].z += v * wv.z; acc[t].w += v * wv.w;
            }
        }
    }

    float4 bv = *(const float4*)(bias + q * 4);
#pragma unroll
    for (int t = 0; t < NPT; ++t) {
        acc[t].x = fmaxf(acc[t].x + bv.x, 0.f);
        acc[t].y = fmaxf(acc[t].y + bv.y, 0.f);
        acc[t].z = fmaxf(acc[t].z + bv.z, 0.f);
        acc[t].w = fmaxf(acc[t].w + bv.w, 0.f);
    }

    if (!FUSE_POOL) {
        if (BF16OUT) {
            ushort* ob = (ushort*)out;
#pragma unroll
            for (int t = 0; t < NPT; ++t) {
                long n = nbase + t;
                if (n < N)
                    *(ushort4*)(ob + n * FOUT + q * 4) =
                        make_ushort4(f2bf(acc[t].x), f2bf(acc[t].y),
                                     f2bf(acc[t].z), f2bf(acc[t].w));
            }
        } else {
            float* of = (float*)out;
#pragma unroll
            for (int t = 0; t < NPT; ++t) {
                long n = nbase + t;
                if (n < N) *(float4*)(of + n * FOUT + q * 4) = acc[t];
            }
        }
        return;
    }

    // ---- hierarchical pool ----
#pragma unroll
    for (int t = 0; t < NPT; ++t) {
        long n = nbase + t;
        if (n < N) {
            unsigned int bx = __float_as_uint(acc[t].x), by = __float_as_uint(acc[t].y);
            unsigned int bz = __float_as_uint(acc[t].z), bw = __float_as_uint(acc[t].w);
            int rel = batch[n] - gfirst;
            if (rel < 2) {
                unsigned int* d = gma + rel * FOUT + q * 4;
                atomicMax(d + 0, bx); atomicMax(d + 1, by);
                atomicMax(d + 2, bz); atomicMax(d + 3, bw);
            } else {
                unsigned int* d = g + (long)batch[n] * FOUT + q * 4;
                atomicMax(d + 0, bx); atomicMax(d + 1, by);
                atomicMax(d + 2, bz); atomicMax(d + 3, bw);
            }
        }
    }
    __syncthreads();
    for (int i = threadIdx.x; i < 2 * FOUT; i += BLK) {
        unsigned int v = gma[i];
        if (v) atomicMax(&g[(long)(gfirst + i / FOUT) * FOUT + (i % FOUT)], v);
    }
}

// one block per graph: relu(g@Wfc1+bfc1) @ Wfc2 + bfc2 -> softmax
__global__ void fc_kernel(const float* __restrict__ g, const float* __restrict__ Wfc1,
                          const float* __restrict__ bfc1, const float* __restrict__ Wfc2,
                          const float* __restrict__ bfc2, float* __restrict__ out) {
    __shared__ float gs[128];
    __shared__ float red0[256], red1[256];
    int b = blockIdx.x, tid = threadIdx.x;
    if (tid < 128) gs[tid] = g[b * 128 + tid];
    __syncthreads();
    float h0 = bfc1[tid], h1 = bfc1[tid + 256];
    for (int k = 0; k < 128; ++k) {
        float gv = gs[k];
        h0 += gv * Wfc1[k * 512 + tid];
        h1 += gv * Wfc1[k * 512 + tid + 256];
    }
    h0 = fmaxf(h0, 0.f); h1 = fmaxf(h1, 0.f);
    red0[tid] = h0 * Wfc2[tid * 2 + 0] + h1 * Wfc2[(tid + 256) * 2 + 0];
    red1[tid] = h0 * Wfc2[tid * 2 + 1] + h1 * Wfc2[(tid + 256) * 2 + 1];
    __syncthreads();
    for (int s = 128; s > 0; s >>= 1) {
        if (tid < s) { red0[tid] += red0[tid + s]; red1[tid] += red1[tid + s]; }
        __syncthreads();
    }
    if (tid == 0) {
        float L0 = red0[0] + bfc2[0], L1 = red1[0] + bfc2[1];
        float m = fmaxf(L0, L1);
        float e0 = expf(L0 - m), e1 = expf(L1 - m);
        float inv = 1.f / (e0 + e1);
        out[b * 2 + 0] = e0 * inv;
        out[b * 2 + 1] = e1 * inv;
    }
}

extern "C" void kernel_launch(void* const* d_in, const int* in_sizes, int n_in,
                              void* d_out, int out_size, void* d_ws, size_t ws_size,
                              hipStream_t stream) {
    const float* x     = (const float*)d_in[0];
    const int*   ei    = (const int*)d_in[1];
    const float* ew    = (const float*)d_in[2];
    const int*   batch = (const int*)d_in[3];
    const float* W1    = (const float*)d_in[4];
    const float* b1    = (const float*)d_in[5];
    const float* W2    = (const float*)d_in[6];
    const float* b2    = (const float*)d_in[7];
    const float* W3    = (const float*)d_in[8];
    const float* b3    = (const float*)d_in[9];
    const float* Wfc1  = (const float*)d_in[10];
    const float* bfc1  = (const float*)d_in[11];
    const float* Wfc2  = (const float*)d_in[12];
    const float* bfc2  = (const float*)d_in[13];

    const int N = in_sizes[3];      // 100000
    const int E = in_sizes[2];      // 1600000
    const int* row = ei;
    const int* col = ei + E;

    char* ws = (char*)d_ws;
    float* dinv   = (float*)ws;              ws += align256((size_t)N * 4);
    unsigned long long* packed = (unsigned long long*)ws; ws += align256((size_t)N * 8);
    int*   offs   = (int*)ws;                ws += align256((size_t)(N + 1) * 4);
    int*   bsums  = (int*)ws;                ws += align256((size_t)1024 * 4);
    int2*  perm   = (int2*)ws;               ws += align256((size_t)E * 8);
    float* bufA   = (float*)ws;              ws += align256((size_t)N * 128 * 4);  // agg f32
    ushort* bufH  = (ushort*)ws;             ws += align256((size_t)N * 128 * 2);  // H bf16
    ushort* xbf   = (ushort*)ws;             ws += align256((size_t)N * 40 * 2);   // x bf16
    float* g      = (float*)ws;              ws += align256((size_t)512 * 128 * 4);
    int*   rank   = (int*)bufA;   // rank[E] (6.4MB) aliases bufA — dead before gather1

    const int B = 256;
    const int nScanBlocks = cdiv(N, SCHUNK);   // 98 for N=100000 (<= 1024)
    const int nx4 = N * 10;                    // float4 groups of x (N*40 floats)

    // --- gcn_norm + CSR build (f2bf rides inside deg_count) ---
    hipMemsetAsync(packed, 0, (size_t)N * 8, stream);
    long dcThreads = (long)E > (long)nx4 ? (long)E : (long)nx4;
    deg_count_kernel<<<cdiv(dcThreads, B), B, 0, stream>>>(col, ew, packed, rank, E,
                                                           x, xbf, nx4);
    scanA_kernel<<<nScanBlocks, B, 0, stream>>>(packed, dinv, bsums, N);
    scanB_kernel<<<1, 1024, 0, stream>>>(bsums, offs, nScanBlocks, N,
                                         (float4*)g, 512 * 128 / 4);
    scanC_kernel<<<nScanBlocks, B, 0, stream>>>(packed, bsums, offs, N);
    fill_kernel<<<cdiv(E, B), B, 0, stream>>>(row, col, ew, rank, dinv, offs, perm, E);

    // --- conv1: agg = A*x (40-wide bf16), H1 = relu(agg@W1 + b1) -> bufH (bf16) ---
    gather_kernel<40><<<cdiv((long)N * 5, B), B, 0, stream>>>(
        offs, perm, xbf, dinv, bufA, N);
    gemm_kernel<40, 40, 320, false, true><<<cdiv(N, 128), 320, 0, stream>>>(
        bufA, W1, b1, bufH, nullptr, nullptr, N);

    // --- conv2: agg = A*H1 (40-wide bf16), H2 = relu(agg@W2 + b2) -> bufH (bf16) ---
    gather_kernel<40><<<cdiv((long)N * 5, B), B, 0, stream>>>(
        offs, perm, bufH, dinv, bufA, N);
    gemm_kernel<40, 80, 320, false, true><<<cdiv(N, 64), 320, 0, stream>>>(
        bufA, W2, b2, bufH, nullptr, nullptr, N);

    // --- conv3: agg = A*H2 (80-wide bf16), pool(relu(agg@W3 + b3)) -> g ---
    gather_kernel<80><<<cdiv((long)N * 10, B), B, 0, stream>>>(
        offs, perm, bufH, dinv, bufA, N);
    gemm_kernel<80, 128, 256, true, false><<<cdiv(N, 32), 256, 0, stream>>>(
        bufA, W3, b3, nullptr, batch, (unsigned int*)g, N);

    // --- MLP + softmax ---
    fc_kernel<<<512, 256, 0, stream>>>(g, Wfc1, bfc1, Wfc2, bfc2, (float*)d_out);
}